// Round 12
// baseline (346.952 us; speedup 1.0000x reference)
//
#include <hip/hip_runtime.h>

typedef _Float16 f16;
typedef _Float16 f16x4 __attribute__((ext_vector_type(4)));
typedef _Float16 f16x8 __attribute__((ext_vector_type(8)));
typedef float f32x4 __attribute__((ext_vector_type(4)));

constexpr int SP = 65536;  // 16^4

#define GLD16(g, l) __builtin_amdgcn_global_load_lds( \
  (const __attribute__((address_space(1))) void*)(g), \
  (__attribute__((address_space(3))) void*)(l), 16, 0, 0)

// ---------------------------------------------------------------------------
// ws layout (half-element offsets):
//   w1t 0 / w2t 3072 / w3t 168960 / w4t 334848 / zpage 376320 / a1 376448
//   a2 = a1 + 4194304;  a3 aliases a1.
// ---------------------------------------------------------------------------
__global__ __launch_bounds__(256) void wtrans_k(
    const float* __restrict__ w1, const float* __restrict__ w2,
    const float* __restrict__ w3, const float* __restrict__ w4,
    f16* __restrict__ wt)
{
  int i = blockIdx.x * 256 + threadIdx.x;
  if (i < 3072) {
    int co = i / 96, k = i - co * 96;
    wt[i] = (k < 81) ? (f16)w1[co * 81 + k] : (f16)0.f;
  } else if (i < 168960) {
    int j = i - 3072;
    int t = j >> 11, r = j & 2047;
    int co = r >> 5, ci = r & 31;
    wt[i] = (f16)w2[(co * 32 + ci) * 81 + t];
  } else if (i < 334848) {
    int j = i - 168960;
    int t = j >> 11, r = j & 2047;
    int co = r >> 6, ci = r & 63;
    wt[i] = (f16)w3[(co * 64 + ci) * 81 + t];
  } else if (i < 376320) {
    int j = i - 334848;
    int t = j >> 9, r = j & 511;
    int co = r >> 5, ci = r & 31;
    wt[i] = (co == 0) ? (f16)w4[ci * 81 + t] : (f16)0.f;
  } else if (i < 376448) {
    wt[i] = (f16)0.f;                 // zero page
  }
}

// 512-block XCD swizzle (layer 1): verified FETCH 132MB -> 12.6MB.
__device__ inline int xcd_swizzle512(int raw) { return (raw & 7) * 64 + (raw >> 3); }

// ---------------------------------------------------------------------------
// Layer 1 (unchanged).
// ---------------------------------------------------------------------------
__global__ __launch_bounds__(256) void conv_l1_k(
    const float* __restrict__ x, const f16* __restrict__ w1t,
    const float* __restrict__ bias, f16* __restrict__ aout)
{
  __shared__ float H1[9 * 324];
  __shared__ f16 Bexp[256 * 104];
  const int tid = threadIdx.x;
  const int bid = xcd_swizzle512(blockIdx.x);
  const int b = bid >> 8;
  const int d1 = (bid >> 4) & 15, d2 = bid & 15;
  const float* xb = x + b * SP;

  for (int idx = tid; idx < 9 * 324; idx += 256) {
    int e = idx / 324, c = idx - e * 324;
    int h3 = c / 18, h4 = c - h3 * 18;
    int e1 = e / 3, e2 = e - e1 * 3;
    int dd1 = d1 + e1 - 1, dd2 = d2 + e2 - 1;
    int dd3 = h3 - 1, dd4 = h4 - 1;
    float v = 0.f;
    if (((unsigned)dd1 < 16u) & ((unsigned)dd2 < 16u) &
        ((unsigned)dd3 < 16u) & ((unsigned)dd4 < 16u))
      v = xb[((dd1 * 16 + dd2) * 16 + dd3) * 16 + dd4];
    H1[idx] = v;
  }
  __syncthreads();
  {
    int d3 = tid >> 4, d4 = tid & 15;
    f16* bp = Bexp + tid * 104;
    #pragma unroll
    for (int k = 0; k < 96; ++k) {
      float v = 0.f;
      if (k < 81) {
        int e = k / 9, rem = k - e * 9;
        int o3 = rem / 3, o4 = rem - o3 * 3;
        v = H1[e * 324 + (d3 + o3) * 18 + (d4 + o4)];
      }
      bp[k] = (f16)v;
    }
  }
  __syncthreads();

  const int lane = tid & 63, wave = tid >> 6;
  const int lm = lane & 15, kp = lane >> 4;
  f32x4 acc[2][4] = {};
  #pragma unroll
  for (int k0 = 0; k0 < 96; k0 += 32) {
    f16x8 a0 = *(const f16x8*)(w1t + lm * 96 + k0 + kp * 8);
    f16x8 a1 = *(const f16x8*)(w1t + (16 + lm) * 96 + k0 + kp * 8);
    #pragma unroll
    for (int nt = 0; nt < 4; ++nt) {
      int n = (wave * 4 + nt) * 16 + lm;
      f16x8 bf = *(const f16x8*)(Bexp + n * 104 + k0 + kp * 8);
      acc[0][nt] = __builtin_amdgcn_mfma_f32_16x16x32_f16(a0, bf, acc[0][nt], 0, 0, 0);
      acc[1][nt] = __builtin_amdgcn_mfma_f32_16x16x32_f16(a1, bf, acc[1][nt], 0, 0, 0);
    }
  }
  #pragma unroll
  for (int mt = 0; mt < 2; ++mt) {
    int co = mt * 16 + kp * 4;
    const float* bp = bias + co;
    #pragma unroll
    for (int nt = 0; nt < 4; ++nt) {
      int d3 = wave * 4 + nt;
      f16x4 pk;
      #pragma unroll
      for (int r = 0; r < 4; ++r)
        pk[r] = (f16)fmaxf(acc[mt][nt][r] + bp[r], 0.f);
      *(f16x4*)(aout + (bid * 256 + d3 * 16 + lm) * 32 + co) = pk;
    }
  }
}

// ---------------------------------------------------------------------------
// Layers 2..4, ROUND 11: HALF-PLANE blocks to double TLP (the one untested
// lever; r3-r10's six schedule variants all plateaued at ~92us with every
// pipe idle and 2 waves/SIMD). 1024 blocks x 4 waves; wave owns 2 d3-rows.
// Halo: 10 rows x 18 cols x 64B cells = 11.5KB, double-buffered (24.6KB LDS)
// -> 4 blocks/CU = 16 waves/CU = 4 waves/SIMD.
// Schedule SIMPLIFIED back to r3 form (elaborate A/B pipelining was defeated
// by the compiler every time): per stage
//   vmcnt(0) [only halo(s) in flight - must complete anyway] -> barrier ->
//   issue halo(s+1) [overlaps whole stage] -> 3 x { A-loads; B-reads; MFMA }.
// Zero-page keeps GLD count wave-uniform (3/stage).
// ---------------------------------------------------------------------------
template<int CIN, int COUTP, bool RELU, bool FINAL, int WPE>
__global__ __launch_bounds__(256, WPE) void conv_half_k(
    const f16* __restrict__ ain, const f16* __restrict__ wt,
    const float* __restrict__ bias, const f16* __restrict__ zpage,
    f16* __restrict__ aout, float* __restrict__ fout)
{
  constexpr int MT = COUTP / 16;
  constexpr int NCK = CIN / 32;
  constexpr int NSTAGE = NCK * 9;
  constexpr int BUFH = 768 * 8;          // halves: 768 16B-units = 12,288 B
  __shared__ f16 hal[2 * BUFH];          // 24,576 B

  const int tid = threadIdx.x, lane = tid & 63, wave = tid >> 6;
  const int raw = blockIdx.x;
  const int swz = (raw & 7) * 128 + (raw >> 3);   // XCD k: planes [64k,64k+64)
  const int plane = swz >> 1;
  const int r0 = (swz & 1) * 8;          // this block's d3 rows: r0..r0+7
  const int b = plane >> 8, d1 = (plane >> 4) & 15, d2 = plane & 15;
  const int lm = lane & 15, kp = lane >> 4;

  f32x4 acc[MT][2] = {};

  auto issue_halo = [&](int s) {
    int ck = (NCK == 2 && s >= 9) ? 1 : 0;
    int e = s - ck * 9;
    int e1 = e / 3, e2 = e - e1 * 3;
    int dd1 = d1 + e1 - 1, dd2 = d2 + e2 - 1;
    bool pok = ((unsigned)dd1 < 16u) & ((unsigned)dd2 < 16u);
    const f16* pbase = ain + ((size_t)((b * 16 + dd1) * 16 + dd2) * 256) * CIN + ck * 32;
    f16* dst0 = hal + (s & 1) * BUFH;
    #pragma unroll
    for (int j = 0; j < 3; ++j) {
      int u = j * 256 + wave * 64 + lane;          // 16B-unit slot, 768/buffer
      int cell = u >> 2, q = u & 3;                // cell < 192 (180 real)
      int h3 = cell / 18, h4 = cell - h3 * 18;     // h3 0..9
      int dd3 = r0 - 1 + h3, dd4 = h4 - 1;
      bool ok = pok & (cell < 180) & ((unsigned)dd3 < 16u) & ((unsigned)dd4 < 16u);
      const f16* src = ok ? (pbase + (size_t)(dd3 * 16 + dd4) * CIN + q * 8) : zpage;
      GLD16(src, dst0 + (j * 256 + wave * 64) * 8);   // wave-uniform base
    }
  };

  issue_halo(0);
  for (int s = 0; s < NSTAGE; ++s) {
    // Only halo(s) (own 3 GLDs) is in flight here; it must complete now.
    asm volatile("s_waitcnt vmcnt(0)" ::: "memory");
    __builtin_amdgcn_s_barrier();
    if (s + 1 < NSTAGE) issue_halo(s + 1);         // overlaps entire stage

    int ck = (NCK == 2 && s >= 9) ? 1 : 0;
    int e = s - ck * 9;
    const f16* buf = hal + (s & 1) * BUFH;
    const f16* wb = wt + ((size_t)(e * 9) * COUTP + lm) * CIN + ck * 32 + kp * 8;
    #pragma unroll
    for (int g = 0; g < 3; ++g) {
      f16x8 A[3 * MT];
      #pragma unroll
      for (int t = 0; t < 3; ++t)
        #pragma unroll
        for (int mt = 0; mt < MT; ++mt)
          A[t * MT + mt] = *(const f16x8*)(wb + (size_t)((g * 3 + t) * COUTP + mt * 16) * CIN);
      #pragma unroll
      for (int nt = 0; nt < 2; ++nt)
        #pragma unroll
        for (int o4 = 0; o4 < 3; ++o4) {
          f16x8 bf = *(const f16x8*)(buf + ((wave * 2 + nt + g) * 18 + lm + o4) * 32 + kp * 8);
          #pragma unroll
          for (int mt = 0; mt < MT; ++mt)
            acc[mt][nt] = __builtin_amdgcn_mfma_f32_16x16x32_f16(
                A[o4 * MT + mt], bf, acc[mt][nt], 0, 0, 0);
        }
    }
  }

  // ---- epilogue ----
  if (FINAL) {
    if (kp == 0) {
      float bv = bias[0];
      #pragma unroll
      for (int nt = 0; nt < 2; ++nt) {
        int r = r0 + wave * 2 + nt;
        fout[plane * 256 + r * 16 + lm] = acc[0][nt][0] + bv;
      }
    }
  } else {
    #pragma unroll
    for (int mt = 0; mt < MT; ++mt) {
      int co = mt * 16 + kp * 4;
      const float* bp = bias + co;
      #pragma unroll
      for (int nt = 0; nt < 2; ++nt) {
        int r = r0 + wave * 2 + nt;
        f16x4 pk;
        #pragma unroll
        for (int q = 0; q < 4; ++q) {
          float v = acc[mt][nt][q] + bp[q];
          if (RELU) v = fmaxf(v, 0.f);
          pk[q] = (f16)v;
        }
        *(f16x4*)(aout + ((size_t)(plane * 256 + r * 16 + lm)) * COUTP + co) = pk;
      }
    }
  }
}

extern "C" void kernel_launch(void* const* d_in, const int* in_sizes, int n_in,
                              void* d_out, int out_size, void* d_ws, size_t ws_size,
                              hipStream_t stream)
{
  (void)in_sizes; (void)n_in; (void)out_size; (void)ws_size;
  const float* x  = (const float*)d_in[0];
  const float* w1 = (const float*)d_in[1];
  const float* b1 = (const float*)d_in[2];
  const float* w2 = (const float*)d_in[3];
  const float* b2 = (const float*)d_in[4];
  const float* w3 = (const float*)d_in[5];
  const float* b3 = (const float*)d_in[6];
  const float* w4 = (const float*)d_in[7];
  const float* b4 = (const float*)d_in[8];

  f16* ws  = (f16*)d_ws;
  f16* w1t = ws;
  f16* w2t = ws + 3072;
  f16* w3t = ws + 168960;
  f16* w4t = ws + 334848;
  f16* zpg = ws + 376320;
  f16* a1  = ws + 376448;
  f16* a2  = a1 + (size_t)2 * SP * 32;
  f16* a3  = a1;                      // a1 dead after layer 2 reads it
  float* out = (float*)d_out;

  wtrans_k<<<1471, 256, 0, stream>>>(w1, w2, w3, w4, ws);
  conv_l1_k<<<512, 256, 0, stream>>>(x, w1t, b1, a1);
  conv_half_k<32, 64, true,  false, 3><<<1024, 256, 0, stream>>>(a1, w2t, b2, zpg, a2, nullptr);
  conv_half_k<64, 32, true,  false, 4><<<1024, 256, 0, stream>>>(a2, w3t, b3, zpg, a3, nullptr);
  conv_half_k<32, 16, false, true,  4><<<1024, 256, 0, stream>>>(a3, w4t, b4, zpg, nullptr, out);
}